// Round 2
// baseline (404.489 us; speedup 1.0000x reference)
//
#include <hip/hip_runtime.h>

// Problem constants
#define BB 4
#define GN 2048
#define DD 256
#define GG (GN * GN)            // 4194304

// d_out float offsets (reference return order, flattened)
#define OFF_E   0u
#define OFF_INT 2097152u        // B*G*D
#define OFF_SP  18874368u       // + B*G*G
#define OFF_RG  35651584u
#define OFF_GP  52428800u
#define OFF_CP  56623104u
#define OFF_L0  69206016u

// clang-native 4-float vector: __builtin_nontemporal_* requires this,
// HIP's float4 (HIP_vector_type struct) is rejected.
typedef float f4 __attribute__((ext_vector_type(4)));

__device__ __forceinline__ float sigf(float x) { return 1.0f / (1.0f + __expf(-x)); }

__device__ __forceinline__ int argmax3(float a, float b, float c) {
  int idx = 0; float best = a;
  if (b > best) { best = b; idx = 1; }
  if (c > best) { idx = 2; }
  return idx;
}

// ---------------------------------------------------------------------------
// Kernel 1: embedding gather + the two 256-length dots (s_i, s_j).
// One wave per (b,g) row; b_proj is folded into s_i here so the streaming
// kernel never touches bptr. Thread (0,0) zeroes the l0 accumulator.
// ---------------------------------------------------------------------------
__global__ __launch_bounds__(256) void k_embed(
    const int* __restrict__ gene_ids, const float* __restrict__ emb,
    const float* __restrict__ w, const float* __restrict__ bptr,
    float* __restrict__ e_out, float* __restrict__ s_i, float* __restrict__ s_j,
    float* __restrict__ l0) {
  if (blockIdx.x == 0 && threadIdx.x == 0) *l0 = 0.0f;

  const int row  = blockIdx.x * 4 + (threadIdx.x >> 6);  // 0 .. B*G-1
  const int lane = threadIdx.x & 63;
  const int gid  = gene_ids[row];

  const f4 v = ((const f4*)(emb + (size_t)gid * DD))[lane];
  __builtin_nontemporal_store(v, (f4*)(e_out + (size_t)row * DD) + lane);

  const f4 w0 = ((const f4*)w)[lane];          // w_proj[:256]
  const f4 w1 = ((const f4*)(w + DD))[lane];   // w_proj[256:]
  float di = v.x * w0.x + v.y * w0.y + v.z * w0.z + v.w * w0.w;
  float dj = v.x * w1.x + v.y * w1.y + v.z * w1.z + v.w * w1.w;
#pragma unroll
  for (int off = 32; off > 0; off >>= 1) {
    di += __shfl_down(di, off);
    dj += __shfl_down(dj, off);
  }
  if (lane == 0) { s_i[row] = di + bptr[0]; s_j[row] = dj; }
}

// ---------------------------------------------------------------------------
// Kernel 2 (read-heavy): gate_probs, class one-hots, l0, and a packed 1-byte
// code per pair (bit0 = gate, bits1-2 = argmax) for the streaming kernel.
// cl loads / cp stores staged through LDS for full 16B/lane coalescing.
// Only 2 __syncthreads: the one-hot overwrite hits thread-private LDS slots
// (slot m is read and re-written only by thread m/3), so no barrier between.
// ---------------------------------------------------------------------------
__global__ __launch_bounds__(256) void k_gate(
    const float* __restrict__ gl, const float* __restrict__ cl,
    float* __restrict__ gate_out, float* __restrict__ cp_out,
    unsigned* __restrict__ code, float* __restrict__ l0) {
  __shared__ f4 lds[768];   // 12 KB: block's cl slab, reused for cp

  const int tid = threadIdx.x;
  const int t   = blockIdx.x * 256 + tid;          // 0 .. GG/4-1
  const size_t base = (size_t)blockIdx.x * 768;    // f4 units

  // ---- coalesced cl load -> LDS (nontemporal: 48 MB single-use stream) ----
  const f4* cl4 = (const f4*)cl;
#pragma unroll
  for (int k = 0; k < 3; ++k)
    lds[tid + k * 256] = __builtin_nontemporal_load(cl4 + base + tid + k * 256);

  // ---- gate (independent of LDS traffic) ----
  const f4 g = __builtin_nontemporal_load((const f4*)gl + t);
  const float gx = g.x > 0.0f ? 1.0f : 0.0f;
  const float gy = g.y > 0.0f ? 1.0f : 0.0f;
  const float gz = g.z > 0.0f ? 1.0f : 0.0f;
  const float gw = g.w > 0.0f ? 1.0f : 0.0f;

  __syncthreads();
  const f4 c0 = lds[tid * 3];
  const f4 c1 = lds[tid * 3 + 1];
  const f4 c2 = lds[tid * 3 + 2];

  const int i0 = argmax3(c0.x, c0.y, c0.z);
  const int i1 = argmax3(c0.w, c1.x, c1.y);
  const int i2 = argmax3(c1.z, c1.w, c2.x);
  const int i3 = argmax3(c2.y, c2.z, c2.w);

  // in-place one-hot overwrite of this thread's own slots (no barrier needed)
  lds[tid * 3]     = (f4){(float)(i0 == 0), (float)(i0 == 1), (float)(i0 == 2), (float)(i1 == 0)};
  lds[tid * 3 + 1] = (f4){(float)(i1 == 1), (float)(i1 == 2), (float)(i2 == 0), (float)(i2 == 1)};
  lds[tid * 3 + 2] = (f4){(float)(i2 == 2), (float)(i3 == 0), (float)(i3 == 1), (float)(i3 == 2)};

  // gate + packed code stores (hide under the LDS round-trip)
  __builtin_nontemporal_store((f4){gx, gy, gz, gw}, (f4*)gate_out + t);
  const unsigned b0 = (unsigned)(g.x > 0.0f) | ((unsigned)i0 << 1);
  const unsigned b1 = (unsigned)(g.y > 0.0f) | ((unsigned)i1 << 1);
  const unsigned b2 = (unsigned)(g.z > 0.0f) | ((unsigned)i2 << 1);
  const unsigned b3 = (unsigned)(g.w > 0.0f) | ((unsigned)i3 << 1);
  code[t] = b0 | (b1 << 8) | (b2 << 16) | (b3 << 24);  // regular store: k3 re-reads via L2

  __syncthreads();
  f4* cp4 = (f4*)cp_out;
#pragma unroll
  for (int k = 0; k < 3; ++k)
    __builtin_nontemporal_store(lds[tid + k * 256], cp4 + base + tid + k * 256);

  // ---- l0_reg = sum(sigmoid(gate_logits)) ----
  float s = sigf(g.x) + sigf(g.y) + sigf(g.z) + sigf(g.w);
#pragma unroll
  for (int off = 32; off > 0; off >>= 1) s += __shfl_down(s, off);
  __shared__ float part[4];
  if ((tid & 63) == 0) part[tid >> 6] = s;
  __syncthreads();
  if (tid == 0) atomicAdd(l0, part[0] + part[1] + part[2] + part[3]);
}

// ---------------------------------------------------------------------------
// Kernel 3 (pure streaming, fill-like): reads 4 MB of packed codes + 32 KB
// s_i/s_j, writes the three 64 MB (B,G,G) streams with nontemporal f4
// stores. Structurally identical to the rocclr fill that hits 80% HBM peak.
// ---------------------------------------------------------------------------
__global__ __launch_bounds__(256) void k_stream(
    const unsigned* __restrict__ code, const float* __restrict__ s_i,
    const float* __restrict__ s_j,
    float* __restrict__ inter, float* __restrict__ sparse, float* __restrict__ reg) {
  const int t  = blockIdx.x * 256 + threadIdx.x;   // 0 .. GG/4-1
  const int j4 = t & (GN / 4 - 1);                 // 0..511
  const int i  = t >> 9;                           // 0..2047

  const unsigned cw = code[t];
  const float gx = (float)(cw & 1u);
  const float vx = (float)(int)((cw >> 1) & 3u) - 1.0f;
  const float gy = (float)((cw >> 8) & 1u);
  const float vy = (float)(int)((cw >> 9) & 3u) - 1.0f;
  const float gz = (float)((cw >> 16) & 1u);
  const float vz = (float)(int)((cw >> 17) & 3u) - 1.0f;
  const float gw = (float)((cw >> 24) & 1u);
  const float vw = (float)(int)((cw >> 25) & 3u) - 1.0f;

#pragma unroll
  for (int b = 0; b < BB; ++b) {
    const float si = s_i[b * GN + i];                    // b_proj already folded in
    const f4    sj = ((const f4*)(s_j + b * GN))[j4];    // L1/L2-hot (32 KB)
    const f4 it4 = {si + sj.x, si + sj.y, si + sj.z, si + sj.w};
    const f4 sp4 = {it4.x * gx, it4.y * gy, it4.z * gz, it4.w * gw};
    const f4 rg4 = {sp4.x * vx, sp4.y * vy, sp4.z * vz, sp4.w * vw};
    const size_t o = (size_t)b * (GG / 4) + t;
    __builtin_nontemporal_store(it4, (f4*)inter + o);
    __builtin_nontemporal_store(sp4, (f4*)sparse + o);
    __builtin_nontemporal_store(rg4, (f4*)reg + o);
  }
}

extern "C" void kernel_launch(void* const* d_in, const int* in_sizes, int n_in,
                              void* d_out, int out_size, void* d_ws, size_t ws_size,
                              hipStream_t stream) {
  const int*   gene_ids = (const int*)d_in[0];
  const float* emb      = (const float*)d_in[1];
  const float* w        = (const float*)d_in[2];
  const float* bptr     = (const float*)d_in[3];
  const float* gl       = (const float*)d_in[4];
  const float* cl       = (const float*)d_in[5];
  float* out = (float*)d_out;

  float*    s_i  = (float*)d_ws;              // B*G floats
  float*    s_j  = s_i + BB * GN;             // B*G floats
  unsigned* code = (unsigned*)(s_j + BB * GN);// GG/4 uints = 4 MB

  k_embed<<<BB * GN / 4, 256, 0, stream>>>(gene_ids, emb, w, bptr, out + OFF_E,
                                           s_i, s_j, out + OFF_L0);
  k_gate<<<GG / 1024, 256, 0, stream>>>(gl, cl, out + OFF_GP, out + OFF_CP,
                                        code, out + OFF_L0);
  k_stream<<<GG / 1024, 256, 0, stream>>>(code, s_i, s_j,
                                          out + OFF_INT, out + OFF_SP, out + OFF_RG);
}

// Round 3
// 387.515 us; speedup vs baseline: 1.0438x; 1.0438x over previous
//
#include <hip/hip_runtime.h>

// Problem constants
#define BB 4
#define GN 2048
#define DD 256
#define GG (GN * GN)            // 4194304

// d_out float offsets (reference return order, flattened)
#define OFF_E   0u
#define OFF_INT 2097152u        // B*G*D
#define OFF_SP  18874368u       // + B*G*G
#define OFF_RG  35651584u
#define OFF_GP  52428800u
#define OFF_CP  56623104u
#define OFF_L0  69206016u

// clang-native 4-float vector (__builtin_nontemporal_* rejects HIP's float4 struct)
typedef float f4 __attribute__((ext_vector_type(4)));

__device__ __forceinline__ float sigf(float x) { return 1.0f / (1.0f + __expf(-x)); }

__device__ __forceinline__ int argmax3(float a, float b, float c) {
  int idx = 0; float best = a;
  if (b > best) { best = b; idx = 1; }
  if (c > best) { idx = 2; }
  return idx;
}

// ---------------------------------------------------------------------------
// Kernel 1: embedding gather + the two 256-length dots (s_i, s_j).
// One wave per (b,g) row; b_proj folded into s_i. Thread (0,0) zeroes l0.
// ---------------------------------------------------------------------------
__global__ __launch_bounds__(256) void k_embed(
    const int* __restrict__ gene_ids, const float* __restrict__ emb,
    const float* __restrict__ w, const float* __restrict__ bptr,
    float* __restrict__ e_out, float* __restrict__ s_i, float* __restrict__ s_j,
    float* __restrict__ l0) {
  if (blockIdx.x == 0 && threadIdx.x == 0) *l0 = 0.0f;

  const int row  = blockIdx.x * 4 + (threadIdx.x >> 6);  // 0 .. B*G-1
  const int lane = threadIdx.x & 63;
  const int gid  = gene_ids[row];

  const f4 v = ((const f4*)(emb + (size_t)gid * DD))[lane];
  __builtin_nontemporal_store(v, (f4*)(e_out + (size_t)row * DD) + lane);

  const f4 w0 = ((const f4*)w)[lane];          // w_proj[:256]
  const f4 w1 = ((const f4*)(w + DD))[lane];   // w_proj[256:]
  float di = v.x * w0.x + v.y * w0.y + v.z * w0.z + v.w * w0.w;
  float dj = v.x * w1.x + v.y * w1.y + v.z * w1.z + v.w * w1.w;
#pragma unroll
  for (int off = 32; off > 0; off >>= 1) {
    di += __shfl_down(di, off);
    dj += __shfl_down(dj, off);
  }
  if (lane == 0) { s_i[row] = di + bptr[0]; s_j[row] = dj; }
}

// ---------------------------------------------------------------------------
// Kernel 2: l0 = sum(sigmoid(gate_logits)). 128 blocks grid-striding 16 MB
// -> only 128 same-address atomics (vs 16384 before: that storm serialized
// at the L2 RMW unit, ~25 cyc each ~= 170 us of drain bounding k_fused/k_gate).
// Runs before k_gate, which also pre-warms gl into L2.
// ---------------------------------------------------------------------------
__global__ __launch_bounds__(256) void k_l0(
    const float* __restrict__ gl, float* __restrict__ l0) {
  const int tid = blockIdx.x * 256 + threadIdx.x;
  const f4* g4 = (const f4*)gl;
  float s = 0.0f;
  for (int idx = tid; idx < GG / 4; idx += 128 * 256) {
    const f4 g = g4[idx];
    s += sigf(g.x) + sigf(g.y) + sigf(g.z) + sigf(g.w);
  }
#pragma unroll
  for (int off = 32; off > 0; off >>= 1) s += __shfl_down(s, off);
  __shared__ float part[4];
  if ((threadIdx.x & 63) == 0) part[threadIdx.x >> 6] = s;
  __syncthreads();
  if (threadIdx.x == 0) atomicAdd(l0, part[0] + part[1] + part[2] + part[3]);
}

// ---------------------------------------------------------------------------
// Kernel 3: gate_probs, class one-hots, and the packed per-pair code.
// NO atomics, no l0 work. cl/cp staged through LDS for 16B/lane coalescing.
// ---------------------------------------------------------------------------
__global__ __launch_bounds__(256) void k_gate(
    const float* __restrict__ gl, const float* __restrict__ cl,
    float* __restrict__ gate_out, float* __restrict__ cp_out,
    unsigned* __restrict__ code) {
  __shared__ f4 lds[768];   // 12 KB: block's cl slab, reused for cp

  const int tid = threadIdx.x;
  const int t   = blockIdx.x * 256 + tid;          // 0 .. GG/4-1
  const size_t base = (size_t)blockIdx.x * 768;    // f4 units

  // ---- coalesced cl load -> LDS ----
  const f4* cl4 = (const f4*)cl;
#pragma unroll
  for (int k = 0; k < 3; ++k)
    lds[tid + k * 256] = __builtin_nontemporal_load(cl4 + base + tid + k * 256);

  // ---- gate (independent of LDS traffic; gl is L2-warm from k_l0) ----
  const f4 g = ((const f4*)gl)[t];
  const float gx = g.x > 0.0f ? 1.0f : 0.0f;
  const float gy = g.y > 0.0f ? 1.0f : 0.0f;
  const float gz = g.z > 0.0f ? 1.0f : 0.0f;
  const float gw = g.w > 0.0f ? 1.0f : 0.0f;

  __syncthreads();
  const f4 c0 = lds[tid * 3];
  const f4 c1 = lds[tid * 3 + 1];
  const f4 c2 = lds[tid * 3 + 2];

  const int i0 = argmax3(c0.x, c0.y, c0.z);
  const int i1 = argmax3(c0.w, c1.x, c1.y);
  const int i2 = argmax3(c1.z, c1.w, c2.x);
  const int i3 = argmax3(c2.y, c2.z, c2.w);

  // in-place one-hot overwrite of this thread's own slots (no barrier needed)
  lds[tid * 3]     = (f4){(float)(i0 == 0), (float)(i0 == 1), (float)(i0 == 2), (float)(i1 == 0)};
  lds[tid * 3 + 1] = (f4){(float)(i1 == 1), (float)(i1 == 2), (float)(i2 == 0), (float)(i2 == 1)};
  lds[tid * 3 + 2] = (f4){(float)(i2 == 2), (float)(i3 == 0), (float)(i3 == 1), (float)(i3 == 2)};

  // gate + packed code stores (hide under the LDS round-trip)
  __builtin_nontemporal_store((f4){gx, gy, gz, gw}, (f4*)gate_out + t);
  const unsigned b0 = (unsigned)(g.x > 0.0f) | ((unsigned)i0 << 1);
  const unsigned b1 = (unsigned)(g.y > 0.0f) | ((unsigned)i1 << 1);
  const unsigned b2 = (unsigned)(g.z > 0.0f) | ((unsigned)i2 << 1);
  const unsigned b3 = (unsigned)(g.w > 0.0f) | ((unsigned)i3 << 1);
  code[t] = b0 | (b1 << 8) | (b2 << 16) | (b3 << 24);  // k_stream re-reads via L2

  __syncthreads();
  f4* cp4 = (f4*)cp_out;
#pragma unroll
  for (int k = 0; k < 3; ++k)
    __builtin_nontemporal_store(lds[tid + k * 256], cp4 + base + tid + k * 256);
}

// ---------------------------------------------------------------------------
// Kernel 4 (pure streaming, fill-like): reads 4 MB packed codes + 32 KB
// s_i/s_j, writes the three 64 MB (B,G,G) streams with nontemporal stores.
// ---------------------------------------------------------------------------
__global__ __launch_bounds__(256) void k_stream(
    const unsigned* __restrict__ code, const float* __restrict__ s_i,
    const float* __restrict__ s_j,
    float* __restrict__ inter, float* __restrict__ sparse, float* __restrict__ reg) {
  const int t  = blockIdx.x * 256 + threadIdx.x;   // 0 .. GG/4-1
  const int j4 = t & (GN / 4 - 1);                 // 0..511
  const int i  = t >> 9;                           // 0..2047

  const unsigned cw = code[t];
  const float gx = (float)(cw & 1u);
  const float vx = (float)(int)((cw >> 1) & 3u) - 1.0f;
  const float gy = (float)((cw >> 8) & 1u);
  const float vy = (float)(int)((cw >> 9) & 3u) - 1.0f;
  const float gz = (float)((cw >> 16) & 1u);
  const float vz = (float)(int)((cw >> 17) & 3u) - 1.0f;
  const float gw = (float)((cw >> 24) & 1u);
  const float vw = (float)(int)((cw >> 25) & 3u) - 1.0f;

#pragma unroll
  for (int b = 0; b < BB; ++b) {
    const float si = s_i[b * GN + i];                    // b_proj already folded in
    const f4    sj = ((const f4*)(s_j + b * GN))[j4];    // L1/L2-hot (32 KB)
    const f4 it4 = {si + sj.x, si + sj.y, si + sj.z, si + sj.w};
    const f4 sp4 = {it4.x * gx, it4.y * gy, it4.z * gz, it4.w * gw};
    const f4 rg4 = {sp4.x * vx, sp4.y * vy, sp4.z * vz, sp4.w * vw};
    const size_t o = (size_t)b * (GG / 4) + t;
    __builtin_nontemporal_store(it4, (f4*)inter + o);
    __builtin_nontemporal_store(sp4, (f4*)sparse + o);
    __builtin_nontemporal_store(rg4, (f4*)reg + o);
  }
}

extern "C" void kernel_launch(void* const* d_in, const int* in_sizes, int n_in,
                              void* d_out, int out_size, void* d_ws, size_t ws_size,
                              hipStream_t stream) {
  const int*   gene_ids = (const int*)d_in[0];
  const float* emb      = (const float*)d_in[1];
  const float* w        = (const float*)d_in[2];
  const float* bptr     = (const float*)d_in[3];
  const float* gl       = (const float*)d_in[4];
  const float* cl       = (const float*)d_in[5];
  float* out = (float*)d_out;

  float*    s_i  = (float*)d_ws;              // B*G floats
  float*    s_j  = s_i + BB * GN;             // B*G floats
  unsigned* code = (unsigned*)(s_j + BB * GN);// GG/4 uints = 4 MB

  k_embed<<<BB * GN / 4, 256, 0, stream>>>(gene_ids, emb, w, bptr, out + OFF_E,
                                           s_i, s_j, out + OFF_L0);
  k_l0<<<128, 256, 0, stream>>>(gl, out + OFF_L0);
  k_gate<<<GG / 1024, 256, 0, stream>>>(gl, cl, out + OFF_GP, out + OFF_CP, code);
  k_stream<<<GG / 1024, 256, 0, stream>>>(code, s_i, s_j,
                                          out + OFF_INT, out + OFF_SP, out + OFF_RG);
}